// Round 5
// baseline (152.557 us; speedup 1.0000x reference)
//
#include <hip/hip_runtime.h>
#include <math.h>

#define NB 2048

__device__ __forceinline__ float signf_(float x) {
    return (x > 0.0f) ? 1.0f : ((x < 0.0f) ? -1.0f : 0.0f);
}

// Fused kernel: per (s,b) pair computes M = (eq@W + bias) * env in f64, then
// a_sign/a_log via ONE 16x16 f64 LU + transposed solve (cofactor identity:
// det(minor_i0) = (-1)^i det(M) (M^-T e0)_i, so the reference's alt (-1)^i
// cancels), then writes out_sign/out_log for the 16x128 eq tile.
// Block = 256 threads = 4 waves; wave w owns pair P = blockIdx*4 + w.
// R4/R5: no eq LDS staging (read global twice, L2-hot); per-wave symmetric LU
// (redundant across the wave's four 16-lane groups); LDS 47.6KB -> 13.8KB.
__global__ __launch_bounds__(256, 4)
void slogcof_kernel(const float* __restrict__ eq,
                    const float* __restrict__ rei,
                    const float* __restrict__ Wm,
                    const float* __restrict__ bias,
                    const float* __restrict__ env_a,
                    const float* __restrict__ env_ion,
                    float* __restrict__ out)
{
    __shared__ double sM[4][16][18];     // per-wave 16x16 M (stride 18)
    __shared__ double sDist[4][16][8];
    __shared__ float  sA[4][2][16];      // [wave][sign/log][n]

    const int tid = threadIdx.x;
    const int w   = tid >> 6;           // wave id = pair slot in block
    const int l   = tid & 63;           // lane
    const int P   = blockIdx.x * 4 + w; // global pair id (4096 total)
    const int s   = P >> 11;            // spin
    const int bb  = P & (NB - 1);       // batch

    const int o16 = l & 15;             // orbital column
    const int q4  = l >> 4;             // 4-row group

    const float* eqp = eq + (size_t)bb * 4096 + s * 2048;

    // ---- distances (f64): 128 values per pair, 2 per lane ----
    #pragma unroll
    for (int rep = 0; rep < 2; ++rep) {
        const int n = (l >> 3) + rep * 8;
        const int i = l & 7;
        const float* rp = rei + (size_t)bb * 768 + s * 384 + n * 24 + i * 3;
        const double x = (double)rp[0], y = (double)rp[1], z = (double)rp[2];
        sDist[w][n][i] = sqrt(x * x + y * y + z * z);
    }
    __syncthreads();

    // ---- linear = eq @ W in f64, direct from global (broadcast-coalesced) ----
    // lane (q4,o16) computes rows 4*q4+j (j=0..3), column o16.
    double accv[4] = {0.0, 0.0, 0.0, 0.0};
    {
        const float* Wp = Wm + s * 2048;
        const float* r0 = eqp + (4 * q4 + 0) * 128;
        const float* r1 = eqp + (4 * q4 + 1) * 128;
        const float* r2 = eqp + (4 * q4 + 2) * 128;
        const float* r3 = eqp + (4 * q4 + 3) * 128;
        #pragma unroll 4
        for (int d0 = 0; d0 < 128; d0 += 4) {
            const float4 a0 = *reinterpret_cast<const float4*>(r0 + d0);
            const float4 a1 = *reinterpret_cast<const float4*>(r1 + d0);
            const float4 a2 = *reinterpret_cast<const float4*>(r2 + d0);
            const float4 a3 = *reinterpret_cast<const float4*>(r3 + d0);
            const double w0 = (double)Wp[(d0 + 0) * 16 + o16];
            const double w1 = (double)Wp[(d0 + 1) * 16 + o16];
            const double w2 = (double)Wp[(d0 + 2) * 16 + o16];
            const double w3 = (double)Wp[(d0 + 3) * 16 + o16];
            accv[0] += (double)a0.x * w0 + (double)a0.y * w1 + (double)a0.z * w2 + (double)a0.w * w3;
            accv[1] += (double)a1.x * w0 + (double)a1.y * w1 + (double)a1.z * w2 + (double)a1.w * w3;
            accv[2] += (double)a2.x * w0 + (double)a2.y * w1 + (double)a2.z * w2 + (double)a2.w * w3;
            accv[3] += (double)a3.x * w0 + (double)a3.y * w1 + (double)a3.z * w2 + (double)a3.w * w3;
        }
    }

    // ---- env (f64) and M ----
    {
        const double bd = (double)bias[s * 16 + o16];
        double ev[4] = {0.0, 0.0, 0.0, 0.0};
        #pragma unroll
        for (int i = 0; i < 8; ++i) {
            const double ea = fabs((double)env_a[s * 128 + i * 16 + o16]);
            const double ei = (double)env_ion[s * 128 + i * 16 + o16];
            #pragma unroll
            for (int j = 0; j < 4; ++j)
                ev[j] += exp(-sDist[w][4 * q4 + j][i] * ea) * ei;
        }
        #pragma unroll
        for (int j = 0; j < 4; ++j)
            sM[w][4 * q4 + j][o16] = (accv[j] + bd) * ev[j];
    }
    __syncthreads();

    // ---- per-wave LU + transposed solve (redundant across the 4 groups) ----
    {
        const int j = o16;    // my original row (each 16-lane group redundant)
        double row[16];
        #pragma unroll
        for (int c = 0; c < 16; ++c) row[c] = sM[w][j][c];
        const double m0 = row[0];

        double logdet = 0.0;
        int dsign = 1;
        int used = 0;
        int mystep = -1;

        // row-per-lane LU with partial pivoting (used-flag, no physical swap).
        // key: unused rows carry bit 5 so ANY unused row (even |v|==0) beats
        // every used row; low 4 bits = lane for tie-break.
        #pragma unroll
        for (int k = 0; k < 16; ++k) {
            unsigned key;
            {
                const float av = (float)fabs(row[k]);
                key = used ? (unsigned)j
                           : ((__float_as_uint(av) & 0xFFFFFFC0u) | 0x20u | (unsigned)j);
            }
            #pragma unroll
            for (int off = 8; off >= 1; off >>= 1) {
                const unsigned k2 = (unsigned)__shfl_xor((int)key, off, 16);
                if (k2 > key) key = k2;
            }
            const int p = (int)(key & 15u);
            const double pivv = __shfl(row[k], p, 16);
            logdet += (double)logf((float)fabs(pivv));
            if (pivv < 0.0) dsign = -dsign;
            else if (pivv == 0.0) dsign = 0;
            if (j == p) { used = 1; mystep = k; }
            const double minv = (pivv != 0.0) ? (1.0 / pivv) : 0.0;
            const double mul = row[k] * minv;
            const int upd = !used;
            #pragma unroll
            for (int c = k + 1; c < 16; ++c) {
                const double pv = __shfl(row[c], p, 16);
                if (upd) row[c] -= mul * pv;
            }
            if (upd) row[k] = mul;   // store L multiplier
        }

        // permutation parity via inversions of the mystep sequence
        int invc = 0;
        #pragma unroll
        for (int j2 = 0; j2 < 16; ++j2) {
            const int s2 = __shfl(mystep, j2, 16);
            if (j2 > j && mystep > s2) invc++;
        }
        #pragma unroll
        for (int off = 8; off >= 1; off >>= 1) invc += __shfl_xor(invc, off, 16);
        if (invc & 1) dsign = -dsign;

        // solve U^T wv = e0 (forward over columns o; lane owns w_{mystep})
        double wv = 0.0;
        #pragma unroll
        for (int o = 0; o < 16; ++o) {
            double c0 = (mystep < o) ? (row[o] * wv) : 0.0;
            #pragma unroll
            for (int off = 8; off >= 1; off >>= 1) c0 += __shfl_xor(c0, off, 16);
            if (mystep == o) wv = (((o == 0) ? 1.0 : 0.0) - c0) / row[o];
        }
        // solve L^T vv = wv (backward; unit diagonal); z_j lands lane-local
        double vv = 0.0;
        #pragma unroll
        for (int k = 15; k >= 0; --k) {
            double c0 = (mystep > k) ? (row[k] * vv) : 0.0;
            #pragma unroll
            for (int off = 8; off >= 1; off >>= 1) c0 += __shfl_xor(c0, off, 16);
            if (mystep == k) vv = wv - c0;
        }

        if (l < 16) {
            const double zj = vv;
            const float zs = (zj > 0.0) ? 1.0f : ((zj < 0.0) ? -1.0f : 0.0f);
            const float ms = (m0 > 0.0) ? 1.0f : ((m0 < 0.0) ? -1.0f : 0.0f);
            sA[w][0][j] = ms * (float)dsign * zs;
            sA[w][1][j] = logf((float)fabs(m0)) + (float)logdet + logf((float)fabs(zj));
        }
    }
    __syncthreads();

    // ---- output: out[s][0][b][n][d] = sign(eq)*a_sign ; out[s][1][...] = log|eq| + a_log ----
    float* op0 = out + (size_t)s * 8388608 + (size_t)bb * 2048;
    float* op1 = op0 + 4194304;
    #pragma unroll
    for (int it = 0; it < 8; ++it) {
        const int n  = it * 2 + (l >> 5);
        const int d0 = (l & 31) * 4;
        const float4 x = *reinterpret_cast<const float4*>(eqp + n * 128 + d0);
        const float a_s = sA[w][0][n];
        const float a_l = sA[w][1][n];
        float4 osg, olg;
        osg.x = signf_(x.x) * a_s;  olg.x = logf(fabsf(x.x)) + a_l;
        osg.y = signf_(x.y) * a_s;  olg.y = logf(fabsf(x.y)) + a_l;
        osg.z = signf_(x.z) * a_s;  olg.z = logf(fabsf(x.z)) + a_l;
        osg.w = signf_(x.w) * a_s;  olg.w = logf(fabsf(x.w)) + a_l;
        *reinterpret_cast<float4*>(op0 + n * 128 + d0) = osg;
        *reinterpret_cast<float4*>(op1 + n * 128 + d0) = olg;
    }
}

extern "C" void kernel_launch(void* const* d_in, const int* in_sizes, int n_in,
                              void* d_out, int out_size, void* d_ws, size_t ws_size,
                              hipStream_t stream) {
    (void)in_sizes; (void)n_in; (void)out_size; (void)d_ws; (void)ws_size;
    slogcof_kernel<<<dim3(1024), dim3(256), 0, stream>>>(
        (const float*)d_in[0],   // eq_inputs (B,32,128) f32
        (const float*)d_in[1],   // r_ei (B,32,8,3) f32
        (const float*)d_in[2],   // W (2,128,16) f32
        (const float*)d_in[3],   // b (2,16) f32
        (const float*)d_in[4],   // env_a (2,8,16) f32
        (const float*)d_in[5],   // env_ion (2,8,16) f32
        (float*)d_out);          // (2,2,B,16,128) f32
}

// Round 9
// 136.134 us; speedup vs baseline: 1.1206x; 1.1206x over previous
//
#include <hip/hip_runtime.h>
#include <math.h>

#define NB 2048

typedef double dbl4 __attribute__((ext_vector_type(4)));

__device__ __forceinline__ float signf_(float x) {
    return (x > 0.0f) ? 1.0f : ((x < 0.0f) ? -1.0f : 0.0f);
}

// exp(y) for y in [-45, 0]; rel err ~2e-13. Cody-Waite + deg-10 Taylor.
__device__ __forceinline__ double fast_exp_neg(double y) {
    const double LOG2E  = 1.4426950408889634074;
    const double LN2_HI = 6.93147180369123816490e-01;
    const double LN2_LO = 1.90821492927058770002e-10;
    const double kd = __builtin_rint(y * LOG2E);
    double r = __builtin_fma(-kd, LN2_HI, y);
    r = __builtin_fma(-kd, LN2_LO, r);
    double p = 2.755731922398589e-7;            // 1/10!
    p = __builtin_fma(p, r, 2.755731922398589e-6);
    p = __builtin_fma(p, r, 2.480158730158730e-5);
    p = __builtin_fma(p, r, 1.984126984126984e-4);
    p = __builtin_fma(p, r, 1.388888888888889e-3);
    p = __builtin_fma(p, r, 8.333333333333333e-3);
    p = __builtin_fma(p, r, 4.166666666666667e-2);
    p = __builtin_fma(p, r, 1.666666666666667e-1);
    p = __builtin_fma(p, r, 0.5);
    p = __builtin_fma(p, r, 1.0);
    p = __builtin_fma(p, r, 1.0);
    const long long ek = ((long long)(1023 + (int)kd)) << 52;
    return p * __longlong_as_double(ek);
}

// One wave (64 threads) per (s,b) pair. linear = eq@W via f64 MFMA with a
// RUNTIME LAYOUT PROBE (two extra MFMAs recover each acc slot's true
// (row,col) under any product-form lane permutation — removes the R2/R6
// D-layout hypothesis risk). Then M = (linear + bias)*env (fast f64 exp,
// R3-verified row/col convention), one 16x16 LU + transposed solve
// (cofactor identity; reference's alt (-1)^i cancels), redundant across
// the wave's four 16-lane groups.
__global__ __launch_bounds__(64, 4)
void slogcof_kernel(const float* __restrict__ eq,
                    const float* __restrict__ rei,
                    const float* __restrict__ Wm,
                    const float* __restrict__ bias,
                    const float* __restrict__ env_a,
                    const float* __restrict__ env_ion,
                    float* __restrict__ out)
{
    __shared__ double sM[16][18];
    __shared__ double sDist[16][8];
    __shared__ float  sA[2][16];

    const int l   = threadIdx.x;        // lane
    const int P   = blockIdx.x;         // pair id (4096 total)
    const int s   = P >> 11;            // spin
    const int bb  = P & (NB - 1);       // batch

    const int o16 = l & 15;             // orbital column
    const int q4  = l >> 4;             // group index

    const float* eqp = eq + (size_t)bb * 4096 + s * 2048;

    // ---- distances (f64): 128 values, 2 per lane ----
    #pragma unroll
    for (int rep = 0; rep < 2; ++rep) {
        const int n = (l >> 3) + rep * 8;
        const int i = l & 7;
        const float* rp = rei + (size_t)bb * 768 + s * 384 + n * 24 + i * 3;
        const double x = (double)rp[0], y = (double)rp[1], z = (double)rp[2];
        sDist[n][i] = sqrt(x * x + y * y + z * z);
    }

    // ---- linear = eq @ W via f64 MFMA (two interleaved acc chains) ----
    // Intended: A[m=o16][k=q4] (per K-step), B[k=q4][n=o16] (=Wp[64i+l]).
    double accv[4];
    {
        const float* Wp = Wm + s * 2048;
        dbl4 acc0 = {0.0, 0.0, 0.0, 0.0};
        dbl4 acc1 = {0.0, 0.0, 0.0, 0.0};
        #pragma unroll 8
        for (int i = 0; i < 32; i += 2) {
            const double a0 = (double)eqp[o16 * 128 + 4 * i + q4];
            const double b0 = (double)Wp[64 * i + l];
            acc0 = __builtin_amdgcn_mfma_f64_16x16x4f64(a0, b0, acc0, 0, 0, 0);
            const double a1 = (double)eqp[o16 * 128 + 4 * (i + 1) + q4];
            const double b1 = (double)Wp[64 * (i + 1) + l];
            acc1 = __builtin_amdgcn_mfma_f64_16x16x4f64(a1, b1, acc1, 0, 0, 0);
        }
        #pragma unroll
        for (int r = 0; r < 4; ++r) accv[r] = acc0[r] + acc1[r];
    }

    // ---- layout probes: learn each acc slot's true (row,col) ----
    // Probe R: A = intended-row, B = 1  ->  D[m][n] = 4 * (eq-row at m).
    // Probe C: A = 1, B = intended-col  ->  D[m][n] = 4 * (W-col at n).
    int rowi[4], coli[4];
    {
        dbl4 pr = {0.0, 0.0, 0.0, 0.0};
        dbl4 pc = {0.0, 0.0, 0.0, 0.0};
        pr = __builtin_amdgcn_mfma_f64_16x16x4f64((double)o16, 1.0, pr, 0, 0, 0);
        pc = __builtin_amdgcn_mfma_f64_16x16x4f64(1.0, (double)o16, pc, 0, 0, 0);
        #pragma unroll
        for (int r = 0; r < 4; ++r) {
            rowi[r] = ((int)pr[r]) >> 2;
            coli[r] = ((int)pc[r]) >> 2;
        }
    }

    __syncthreads();   // sDist ready; sM about to be scattered

    // ---- scatter raw linear into sM by probed (row,col) ----
    #pragma unroll
    for (int r = 0; r < 4; ++r) sM[rowi[r]][coli[r]] = accv[r];
    __syncthreads();

    // ---- M = (linear + bias) * env, verified convention: rows 4*q4+jj, col o16 ----
    {
        const double bd = (double)bias[s * 16 + o16];
        double lin[4], ev[4] = {0.0, 0.0, 0.0, 0.0};
        #pragma unroll
        for (int jj = 0; jj < 4; ++jj) lin[jj] = sM[4 * q4 + jj][o16];
        #pragma unroll
        for (int i = 0; i < 8; ++i) {
            const double ea = fabs((double)env_a[s * 128 + i * 16 + o16]);
            const double ei = (double)env_ion[s * 128 + i * 16 + o16];
            #pragma unroll
            for (int jj = 0; jj < 4; ++jj)
                ev[jj] += fast_exp_neg(-sDist[4 * q4 + jj][i] * ea) * ei;
        }
        #pragma unroll
        for (int jj = 0; jj < 4; ++jj)
            sM[4 * q4 + jj][o16] = (lin[jj] + bd) * ev[jj];
    }
    __syncthreads();

    // ---- LU + transposed solve (redundant across the 4 groups) ----
    {
        const int j = o16;    // my original row
        double row[16];
        #pragma unroll
        for (int c = 0; c < 16; ++c) row[c] = sM[j][c];
        const double m0 = row[0];

        double logdet = 0.0;
        int dsign = 1;
        int used = 0;
        int mystep = -1;

        // row-per-lane LU with partial pivoting (used-flag, no physical swap).
        // key: unused rows carry bit 5 so ANY unused row (even |v|==0) beats
        // every used row; low 4 bits = lane for tie-break.
        #pragma unroll
        for (int k = 0; k < 16; ++k) {
            unsigned key;
            {
                const float av = (float)fabs(row[k]);
                key = used ? (unsigned)j
                           : ((__float_as_uint(av) & 0xFFFFFFC0u) | 0x20u | (unsigned)j);
            }
            #pragma unroll
            for (int off = 8; off >= 1; off >>= 1) {
                const unsigned k2 = (unsigned)__shfl_xor((int)key, off, 16);
                if (k2 > key) key = k2;
            }
            const int p = (int)(key & 15u);
            const double pivv = __shfl(row[k], p, 16);
            logdet += (double)logf((float)fabs(pivv));
            if (pivv < 0.0) dsign = -dsign;
            else if (pivv == 0.0) dsign = 0;
            if (j == p) { used = 1; mystep = k; }
            const double minv = (pivv != 0.0) ? (1.0 / pivv) : 0.0;
            const double mul = row[k] * minv;
            const int upd = !used;
            #pragma unroll
            for (int c = k + 1; c < 16; ++c) {
                const double pv = __shfl(row[c], p, 16);
                if (upd) row[c] -= mul * pv;
            }
            if (upd) row[k] = mul;   // store L multiplier
        }

        // permutation parity via inversions of the mystep sequence
        int invc = 0;
        #pragma unroll
        for (int j2 = 0; j2 < 16; ++j2) {
            const int s2 = __shfl(mystep, j2, 16);
            if (j2 > j && mystep > s2) invc++;
        }
        #pragma unroll
        for (int off = 8; off >= 1; off >>= 1) invc += __shfl_xor(invc, off, 16);
        if (invc & 1) dsign = -dsign;

        // solve U^T wv = e0 (forward over columns o; lane owns w_{mystep})
        double wv = 0.0;
        #pragma unroll
        for (int o = 0; o < 16; ++o) {
            double c0 = (mystep < o) ? (row[o] * wv) : 0.0;
            #pragma unroll
            for (int off = 8; off >= 1; off >>= 1) c0 += __shfl_xor(c0, off, 16);
            if (mystep == o) wv = (((o == 0) ? 1.0 : 0.0) - c0) / row[o];
        }
        // solve L^T vv = wv (backward; unit diagonal); z_j lands lane-local
        double vv = 0.0;
        #pragma unroll
        for (int k = 15; k >= 0; --k) {
            double c0 = (mystep > k) ? (row[k] * vv) : 0.0;
            #pragma unroll
            for (int off = 8; off >= 1; off >>= 1) c0 += __shfl_xor(c0, off, 16);
            if (mystep == k) vv = wv - c0;
        }

        if (l < 16) {
            const double zj = vv;
            const float zs = (zj > 0.0) ? 1.0f : ((zj < 0.0) ? -1.0f : 0.0f);
            const float ms = (m0 > 0.0) ? 1.0f : ((m0 < 0.0) ? -1.0f : 0.0f);
            sA[0][j] = ms * (float)dsign * zs;
            sA[1][j] = logf((float)fabs(m0)) + (float)logdet + logf((float)fabs(zj));
        }
    }
    __syncthreads();

    // ---- output: out[s][0][b][n][d] = sign(eq)*a_sign ; out[s][1][...] = log|eq| + a_log ----
    float* op0 = out + (size_t)s * 8388608 + (size_t)bb * 2048;
    float* op1 = op0 + 4194304;
    #pragma unroll
    for (int it = 0; it < 8; ++it) {
        const int n  = it * 2 + (l >> 5);
        const int d0 = (l & 31) * 4;
        const float4 x = *reinterpret_cast<const float4*>(eqp + n * 128 + d0);
        const float a_s = sA[0][n];
        const float a_l = sA[1][n];
        float4 osg, olg;
        osg.x = signf_(x.x) * a_s;  olg.x = logf(fabsf(x.x)) + a_l;
        osg.y = signf_(x.y) * a_s;  olg.y = logf(fabsf(x.y)) + a_l;
        osg.z = signf_(x.z) * a_s;  olg.z = logf(fabsf(x.z)) + a_l;
        osg.w = signf_(x.w) * a_s;  olg.w = logf(fabsf(x.w)) + a_l;
        *reinterpret_cast<float4*>(op0 + n * 128 + d0) = osg;
        *reinterpret_cast<float4*>(op1 + n * 128 + d0) = olg;
    }
}

extern "C" void kernel_launch(void* const* d_in, const int* in_sizes, int n_in,
                              void* d_out, int out_size, void* d_ws, size_t ws_size,
                              hipStream_t stream) {
    (void)in_sizes; (void)n_in; (void)out_size; (void)d_ws; (void)ws_size;
    slogcof_kernel<<<dim3(4096), dim3(64), 0, stream>>>(
        (const float*)d_in[0],   // eq_inputs (B,32,128) f32
        (const float*)d_in[1],   // r_ei (B,32,8,3) f32
        (const float*)d_in[2],   // W (2,128,16) f32
        (const float*)d_in[3],   // b (2,16) f32
        (const float*)d_in[4],   // env_a (2,8,16) f32
        (const float*)d_in[5],   // env_ion (2,8,16) f32
        (float*)d_out);          // (2,2,B,16,128) f32
}

// Round 11
// 126.473 us; speedup vs baseline: 1.2062x; 1.0764x over previous
//
#include <hip/hip_runtime.h>
#include <math.h>

#define NB 2048

typedef double dbl4 __attribute__((ext_vector_type(4)));

__device__ __forceinline__ float signf_(float x) {
    return (x > 0.0f) ? 1.0f : ((x < 0.0f) ? -1.0f : 0.0f);
}

// exp(y) for y in [-45, 0]; rel err ~2e-13. Cody-Waite + deg-10 Taylor.
__device__ __forceinline__ double fast_exp_neg(double y) {
    const double LOG2E  = 1.4426950408889634074;
    const double LN2_HI = 6.93147180369123816490e-01;
    const double LN2_LO = 1.90821492927058770002e-10;
    const double kd = __builtin_rint(y * LOG2E);
    double r = __builtin_fma(-kd, LN2_HI, y);
    r = __builtin_fma(-kd, LN2_LO, r);
    double p = 2.755731922398589e-7;            // 1/10!
    p = __builtin_fma(p, r, 2.755731922398589e-6);
    p = __builtin_fma(p, r, 2.480158730158730e-5);
    p = __builtin_fma(p, r, 1.984126984126984e-4);
    p = __builtin_fma(p, r, 1.388888888888889e-3);
    p = __builtin_fma(p, r, 8.333333333333333e-3);
    p = __builtin_fma(p, r, 4.166666666666667e-2);
    p = __builtin_fma(p, r, 1.666666666666667e-1);
    p = __builtin_fma(p, r, 0.5);
    p = __builtin_fma(p, r, 1.0);
    p = __builtin_fma(p, r, 1.0);
    const long long ek = ((long long)(1023 + (int)kd)) << 52;
    return p * __longlong_as_double(ek);
}

// One wave per (s,b) pair. linear = eq@W via f64 MFMA + runtime layout probe
// (verified R9: passed, absmax 0.375). M^T staged in LDS; then GAUSS-JORDAN
// with partial pivoting on [M^T | e0] — 16 steps replace R9's LU + two
// 16-step transposed solves (same pivots/det: pivot candidates receive
// identical updates as in LU). z = M^-T e0 lands in the augmented column;
// cofactor identity det(minor_i0) = (-1)^i det(M) z_i cancels the
// reference's alt signs. Redundant across the wave's four 16-lane groups.
__global__ __launch_bounds__(64, 4)
void slogcof_kernel(const float* __restrict__ eq,
                    const float* __restrict__ rei,
                    const float* __restrict__ Wm,
                    const float* __restrict__ bias,
                    const float* __restrict__ env_a,
                    const float* __restrict__ env_ion,
                    float* __restrict__ out)
{
    __shared__ double sLin[16][17];   // raw linear, [row][col]
    __shared__ double sMT[16][17];    // M^T: sMT[c][r] = M[r][c]
    __shared__ double sDist[16][8];
    __shared__ double sZ[16];
    __shared__ float  sA[2][16];

    const int l   = threadIdx.x;        // lane
    const int P   = blockIdx.x;         // pair id (4096 total)
    const int s   = P >> 11;            // spin
    const int bb  = P & (NB - 1);       // batch

    const int o16 = l & 15;
    const int q4  = l >> 4;

    const float* eqp = eq + (size_t)bb * 4096 + s * 2048;

    // ---- distances (f64): 128 values, 2 per lane ----
    #pragma unroll
    for (int rep = 0; rep < 2; ++rep) {
        const int n = (l >> 3) + rep * 8;
        const int i = l & 7;
        const float* rp = rei + (size_t)bb * 768 + s * 384 + n * 24 + i * 3;
        const double x = (double)rp[0], y = (double)rp[1], z = (double)rp[2];
        sDist[n][i] = sqrt(x * x + y * y + z * z);
    }

    // ---- linear = eq @ W via f64 MFMA (two interleaved acc chains) ----
    double accv[4];
    {
        const float* Wp = Wm + s * 2048;
        dbl4 acc0 = {0.0, 0.0, 0.0, 0.0};
        dbl4 acc1 = {0.0, 0.0, 0.0, 0.0};
        #pragma unroll 8
        for (int i = 0; i < 32; i += 2) {
            const double a0 = (double)eqp[o16 * 128 + 4 * i + q4];
            const double b0 = (double)Wp[64 * i + l];
            acc0 = __builtin_amdgcn_mfma_f64_16x16x4f64(a0, b0, acc0, 0, 0, 0);
            const double a1 = (double)eqp[o16 * 128 + 4 * (i + 1) + q4];
            const double b1 = (double)Wp[64 * (i + 1) + l];
            acc1 = __builtin_amdgcn_mfma_f64_16x16x4f64(a1, b1, acc1, 0, 0, 0);
        }
        #pragma unroll
        for (int r = 0; r < 4; ++r) accv[r] = acc0[r] + acc1[r];
    }

    // ---- layout probes (R9-verified): recover each acc slot's (row,col) ----
    int rowi[4], coli[4];
    {
        dbl4 pr = {0.0, 0.0, 0.0, 0.0};
        dbl4 pc = {0.0, 0.0, 0.0, 0.0};
        pr = __builtin_amdgcn_mfma_f64_16x16x4f64((double)o16, 1.0, pr, 0, 0, 0);
        pc = __builtin_amdgcn_mfma_f64_16x16x4f64(1.0, (double)o16, pc, 0, 0, 0);
        #pragma unroll
        for (int r = 0; r < 4; ++r) {
            rowi[r] = ((int)pr[r]) >> 2;
            coli[r] = ((int)pc[r]) >> 2;
        }
    }

    #pragma unroll
    for (int r = 0; r < 4; ++r) sLin[rowi[r]][coli[r]] = accv[r];
    __syncthreads();

    // ---- M = (linear + bias) * env; store TRANSPOSED: sMT[col][row] ----
    {
        const double bd = (double)bias[s * 16 + o16];
        double lin[4], ev[4] = {0.0, 0.0, 0.0, 0.0};
        #pragma unroll
        for (int jj = 0; jj < 4; ++jj) lin[jj] = sLin[4 * q4 + jj][o16];
        #pragma unroll
        for (int i = 0; i < 8; ++i) {
            const double ea = fabs((double)env_a[s * 128 + i * 16 + o16]);
            const double ei = (double)env_ion[s * 128 + i * 16 + o16];
            #pragma unroll
            for (int jj = 0; jj < 4; ++jj)
                ev[jj] += fast_exp_neg(-sDist[4 * q4 + jj][i] * ea) * ei;
        }
        #pragma unroll
        for (int jj = 0; jj < 4; ++jj)
            sMT[o16][4 * q4 + jj] = (lin[jj] + bd) * ev[jj];
    }
    __syncthreads();

    // ---- Gauss-Jordan with partial pivoting on [A | e0], A = M^T ----
    // lane j owns row j of A: A[j][c] = M[c][j]. Solution: z[mystep_j] = a_j.
    {
        const int j = o16;
        double row[16];
        #pragma unroll
        for (int c = 0; c < 16; ++c) row[c] = sMT[j][c];
        const double m0 = sMT[0][j];          // M[j][0]
        double a = (j == 0) ? 1.0 : 0.0;

        double logdet = 0.0;
        int dsign = 1;
        int used = 0;
        int mystep = 0;

        #pragma unroll
        for (int k = 0; k < 16; ++k) {
            unsigned key;
            {
                const float av = (float)fabs(row[k]);
                key = used ? (unsigned)j
                           : ((__float_as_uint(av) & 0xFFFFFFC0u) | 0x20u | (unsigned)j);
            }
            #pragma unroll
            for (int off = 8; off >= 1; off >>= 1) {
                const unsigned k2 = (unsigned)__shfl_xor((int)key, off, 16);
                if (k2 > key) key = k2;
            }
            const int p = (int)(key & 15u);
            const double pivv = __shfl(row[k], p, 16);
            logdet += (double)__logf((float)fabs(pivv));
            if (pivv < 0.0) dsign = -dsign;
            else if (pivv == 0.0) dsign = 0;
            const int isp = (j == p);
            if (isp) { used = 1; mystep = k; }
            const double minv = (pivv != 0.0) ? (1.0 / pivv) : 0.0;
            const double f = row[k];
            #pragma unroll
            for (int c = k + 1; c < 16; ++c) {
                const double pr = __shfl(row[c], p, 16) * minv;
                row[c] = isp ? pr : __builtin_fma(-f, pr, row[c]);
            }
            {
                const double pa = __shfl(a, p, 16) * minv;
                a = isp ? pa : __builtin_fma(-f, pa, a);
            }
        }

        // permutation parity via inversions of the mystep sequence
        int invc = 0;
        #pragma unroll
        for (int j2 = 0; j2 < 16; ++j2) {
            const int s2 = __shfl(mystep, j2, 16);
            if (j2 > j && mystep > s2) invc++;
        }
        #pragma unroll
        for (int off = 8; off >= 1; off >>= 1) invc += __shfl_xor(invc, off, 16);
        if (invc & 1) dsign = -dsign;

        // scatter solution: z[mystep_j] = a_j (all groups write same data)
        sZ[mystep] = a;
        __syncthreads();
        const double zj = sZ[j];

        if (l < 16) {
            const float zs = (zj > 0.0) ? 1.0f : ((zj < 0.0) ? -1.0f : 0.0f);
            const float ms = (m0 > 0.0) ? 1.0f : ((m0 < 0.0) ? -1.0f : 0.0f);
            sA[0][j] = ms * (float)dsign * zs;
            sA[1][j] = __logf((float)fabs(m0)) + (float)logdet + __logf((float)fabs(zj));
        }
    }
    __syncthreads();

    // ---- output: out[s][0][b][n][d] = sign(eq)*a_sign ; out[s][1][...] = log|eq| + a_log ----
    float* op0 = out + (size_t)s * 8388608 + (size_t)bb * 2048;
    float* op1 = op0 + 4194304;
    #pragma unroll
    for (int it = 0; it < 8; ++it) {
        const int n  = it * 2 + (l >> 5);
        const int d0 = (l & 31) * 4;
        const float4 x = *reinterpret_cast<const float4*>(eqp + n * 128 + d0);
        const float a_s = sA[0][n];
        const float a_l = sA[1][n];
        float4 osg, olg;
        osg.x = signf_(x.x) * a_s;  olg.x = __logf(fabsf(x.x)) + a_l;
        osg.y = signf_(x.y) * a_s;  olg.y = __logf(fabsf(x.y)) + a_l;
        osg.z = signf_(x.z) * a_s;  olg.z = __logf(fabsf(x.z)) + a_l;
        osg.w = signf_(x.w) * a_s;  olg.w = __logf(fabsf(x.w)) + a_l;
        *reinterpret_cast<float4*>(op0 + n * 128 + d0) = osg;
        *reinterpret_cast<float4*>(op1 + n * 128 + d0) = olg;
    }
}

extern "C" void kernel_launch(void* const* d_in, const int* in_sizes, int n_in,
                              void* d_out, int out_size, void* d_ws, size_t ws_size,
                              hipStream_t stream) {
    (void)in_sizes; (void)n_in; (void)out_size; (void)d_ws; (void)ws_size;
    slogcof_kernel<<<dim3(4096), dim3(64), 0, stream>>>(
        (const float*)d_in[0],   // eq_inputs (B,32,128) f32
        (const float*)d_in[1],   // r_ei (B,32,8,3) f32
        (const float*)d_in[2],   // W (2,128,16) f32
        (const float*)d_in[3],   // b (2,16) f32
        (const float*)d_in[4],   // env_a (2,8,16) f32
        (const float*)d_in[5],   // env_ion (2,8,16) f32
        (float*)d_out);          // (2,2,B,16,128) f32
}